// Round 17
// baseline (188.718 us; speedup 1.0000x reference)
//
#include <hip/hip_runtime.h>

typedef unsigned short u16;
typedef unsigned int u32;
typedef __attribute__((ext_vector_type(4))) int i32x4;
typedef __attribute__((ext_vector_type(4))) float f32x4;
typedef __attribute__((ext_vector_type(4))) u16 u16x4;
typedef __attribute__((ext_vector_type(8))) u16 u16x8;

#define PTOT 131072   // 128 images * 32*32 pixels
#define NREP 16       // stat accumulator replicas (atomic de-contention)

// ---------- helpers ----------
static __device__ __forceinline__ int qi8(float v) {  // round-half-even, clip +-127
  int q = (int)rintf(v * 128.f);
  return max(-127, min(127, q));
}
static __device__ __forceinline__ u16 bf_rne(float v) { // round-nearest-even bf16
  u32 u = __float_as_uint(v);
  u += 0x7fffu + ((u >> 16) & 1u);
  return (u16)(u >> 16);
}
static __device__ __forceinline__ float bf2f(u16 v) {
  return __uint_as_float((u32)v << 16);
}

// ---------- weight quantize + i8 MFMA fragment packing (row-linear K) ----------
struct WPtrs { const float* p[7]; };

__global__ void wpack_kernel(WPtrs wp, char* __restrict__ o) {
  // {byte_off, CIr, KROWP, KH, Co}   (len = NCH*NF*1024)
  static const int S[7][5] = {
      {0,      192, 192, 1, 64},   // b1   NCH=3 NF=4  12288
      {12288,  192, 192, 1, 96},   // b2a  NCH=3 NF=6  18432
      {30720,  96,  320, 3, 128},  // b2b  NCH=15 NF=8 122880
      {153600, 192, 192, 1, 16},   // b3a  NCH=3 NF=1  3072
      {156672, 16,  64,  3, 32},   // b3b  NCH=3 NF=2  6144
      {162816, 32,  128, 3, 32},   // b3c  NCH=6 NF=2  12288
      {175104, 192, 192, 1, 32},   // b4   NCH=3 NF=2  6144
  };
  int idx = blockIdx.x * 256 + threadIdx.x;
  if (idx >= 181248) return;
  int s = 0;
#pragma unroll
  for (int i = 1; i < 7; ++i)
    if (idx >= S[i][0]) s = i;
  int local = idx - S[s][0];
  int CIr = S[s][1], KROWP = S[s][2], KH = S[s][3], Co = S[s][4];
  int j = local & 15, lane = (local >> 4) & 63, f = local >> 10;
  int NF = Co >> 4;
  int c = f / NF, nf = f - c * NF;
  int co = nf * 16 + (lane & 15);
  int k = c * 64 + ((lane >> 4) << 4) + j;
  int r = k / KROWP, kk = k - r * KROWP;
  char val = 0;
  if (kk < 3 * CIr || KH == 1) {
    int kw = (KH == 1) ? 0 : (kk / CIr);
    int ci = (KH == 1) ? kk : (kk - kw * CIr);
    val = (char)qi8(wp.p[s][(((size_t)co * CIr + ci) * KH + r) * KH + kw]);
  }
  o[idx] = val;
}

// ---------- quantize x: NCHW f32 -> NHWC int8 ----------
__global__ __launch_bounds__(256) void quantx_kernel(const float* __restrict__ x,
                                                     char* __restrict__ xq) {
  __shared__ __align__(16) char tile[64][80];
  int n = blockIdx.z, hwb = blockIdx.x * 64, cb = blockIdx.y * 64;
  int lane = threadIdx.x & 63, sub = threadIdx.x >> 6;
#pragma unroll
  for (int i = 0; i < 16; ++i) {
    int c = sub + i * 4;
    float v = x[(((size_t)n * 192 + cb + c) << 10) + hwb + lane];
    tile[lane][c] = (char)qi8(v);
  }
  __syncthreads();
  int t = threadIdx.x, px = t >> 2, c16 = t & 3;
  uint4 v = *(const uint4*)&tile[px][c16 * 16];
  *(uint4*)&xq[(((size_t)n << 10) + hwb + px) * 192 + cb + c16 * 16] = v;
}

// ---------- one channel-chunk of BN+ReLU apply -> f32 NCHW out ----------
static __device__ __forceinline__ void bnout_one(
    const u16* __restrict__ yhbase, const double* __restrict__ stb,
    const float* __restrict__ g, const float* __restrict__ be,
    float* __restrict__ out, int cog, int lco, int chunk, int tid) {
  double s1d = 0., s2d = 0.;
#pragma unroll
  for (int r = 0; r < NREP; ++r) {
    s1d += stb[r * 256 + 2 * lco];
    s2d += stb[r * 256 + 2 * lco + 1];
  }
  double m = s1d * (1.0 / PTOT);
  double v = s2d * (1.0 / PTOT) - m * m;
  double inv = 1.0 / sqrt(v + 1e-5);
  double c0d = (double)g[lco] * inv;
  float c0 = (float)c0d;
  float c1 = (float)((double)be[lco] - m * c0d);

  int p0 = chunk * 4096 + tid * 16;
  int n = p0 >> 10, hw = p0 & 1023;
  const u16* yp = yhbase + (size_t)lco * PTOT + p0;
  float* op = out + (((size_t)(n * 256 + cog + lco)) << 10) + hw;
#pragma unroll
  for (int half = 0; half < 2; ++half) {
    u16x8 r = *(const u16x8*)(yp + half * 8);
    f32x4 a, b;
#pragma unroll
    for (int e = 0; e < 4; ++e) {
      a[e] = fmaxf(fmaf(bf2f(r[e]), c0, c1), 0.f);
      b[e] = fmaxf(fmaf(bf2f(r[e + 4]), c0, c1), 0.f);
    }
    *(f32x4*)(op + half * 8) = a;
    *(f32x4*)(op + half * 8 + 4) = b;
  }
}

// ---------- shared conv epilogue (runtime nfw guard) ----------
template <int NFW, int MF>
static __device__ __forceinline__ void conv_epilogue(
    i32x4 (&acc)[MF][NFW], int nfw, int lane, int wave, int mbase,
    u16* __restrict__ yh, double* __restrict__ stb, int ststride) {
  float yv[MF][NFW][4];
#pragma unroll
  for (int mf = 0; mf < MF; ++mf)
#pragma unroll
    for (int nf = 0; nf < NFW; ++nf)
      if (nf < nfw) {
        int col = nf * 16 + (lane & 15);
        int pix = mbase + mf * 16 + ((lane >> 4) << 2);
        u16x4 o;
#pragma unroll
        for (int r = 0; r < 4; ++r) {
          float v = (float)acc[mf][nf][r] * 6.103515625e-05f;  // 2^-14 (exact)
          yv[mf][nf][r] = v;
          o[r] = bf_rne(v);
        }
        *(u16x4*)&yh[(size_t)col * PTOT + pix] = o;
      }

  float s1[NFW], s2[NFW];
#pragma unroll
  for (int nf = 0; nf < NFW; ++nf) { s1[nf] = 0.f; s2[nf] = 0.f; }
#pragma unroll
  for (int mf = 0; mf < MF; ++mf)
#pragma unroll
    for (int nf = 0; nf < NFW; ++nf)
      if (nf < nfw)
#pragma unroll
        for (int r = 0; r < 4; ++r) {
          float v = yv[mf][nf][r];
          s1[nf] += v;
          s2[nf] += v * v;
        }
#pragma unroll
  for (int m = 16; m <= 32; m <<= 1)
#pragma unroll
    for (int nf = 0; nf < NFW; ++nf) {
      s1[nf] += __shfl_xor(s1[nf], m);
      s2[nf] += __shfl_xor(s2[nf], m);
    }
  __shared__ float red[4][NFW][16][2];
  if (lane < 16)
#pragma unroll
    for (int nf = 0; nf < NFW; ++nf) {
      red[wave][nf][lane][0] = s1[nf];
      red[wave][nf][lane][1] = s2[nf];
    }
  __syncthreads();
  const int t = threadIdx.x;
  if (t < 16 * nfw) {
    int nf = t >> 4, l = t & 15;
    float a = red[0][nf][l][0] + red[1][nf][l][0] + red[2][nf][l][0] + red[3][nf][l][0];
    float b = red[0][nf][l][1] + red[1][nf][l][1] + red[2][nf][l][1] + red[3][nf][l][1];
    int rep = blockIdx.x & (NREP - 1);
    atomicAdd(&stb[rep * ststride + 2 * t], (double)a);
    atomicAdd(&stb[rep * ststride + 2 * t + 1], (double)b);
  }
}

// ---------- merged 1x1 convs {b1,b2a,b3a} + fused pool+b4 (blockIdx.y=3) ----------
// smem union: b<3 -> btile[0..18432); b==3 -> btile[0..6144) + pooled[6144..30720)
__global__ __launch_bounds__(256, 4) void cstat1x1_kernel(
    const char* __restrict__ xq, const char* __restrict__ bpk,
    double* __restrict__ st, u16* __restrict__ yh) {
  constexpr int NFW = 6;
  constexpr int MF = 2;
  __shared__ __align__(16) char smem[30720];

  const int b = blockIdx.y;  // uniform
  const int nfw = (b == 0) ? 4 : (b == 1) ? 6 : (b == 2) ? 1 : 2;
  const int bpo = (b == 0) ? 0 : (b == 1) ? 12288 : (b == 2) ? 153600 : 175104;
  const int sto = (b == 0) ? 0 : (b == 1) ? 256 * NREP
                           : (b == 2) ? 3 * 256 * NREP : 6 * 256 * NREP;
  const int yho = (b == 0) ? 0 : (b == 1) ? 64 : (b == 2) ? 160 : 176;
  const char* bp = bpk + bpo;
  double* stb = st + sto;
  u16* yhb = yh + (size_t)yho * PTOT;

  const int tid = threadIdx.x;
  char* btile = smem;
  char* pooled = smem + 6144;
  const int bsz = nfw * 3 * 1024;
  for (int s = tid * 16; s < bsz; s += 4096)
    *(uint4*)&btile[s] = *(const uint4*)(bp + s);

  const int p0 = blockIdx.x * 128;
  if (b == 3) {  // build pooled tile (identical clamped 3x3 max over xq)
    const int n = p0 >> 10, h0 = (p0 & 1023) >> 5;
    for (int task = tid; task < 128 * 12; task += 256) {
      int px = task / 12, c16 = task - px * 12;
      int h = h0 + (px >> 5), w = px & 31;
      int m[16];
#pragma unroll
      for (int j = 0; j < 16; ++j) m[j] = -127;
      for (int dh = -1; dh <= 1; ++dh) {
        int hh = h + dh; if (hh < 0 || hh > 31) continue;
        for (int dw = -1; dw <= 1; ++dw) {
          int ww = w + dw; if (ww < 0 || ww > 31) continue;
          uint4 v = *(const uint4*)&xq[((size_t)((n << 10) + (hh << 5) + ww)) * 192 +
                                       c16 * 16];
          const char* bb = reinterpret_cast<const char*>(&v);
#pragma unroll
          for (int t = 0; t < 16; ++t) {
            int bv = (int)bb[t];
            m[t] = bv > m[t] ? bv : m[t];
          }
        }
      }
      uint4 o;
      char* ob = reinterpret_cast<char*>(&o);
#pragma unroll
      for (int t = 0; t < 16; ++t) ob[t] = (char)m[t];
      *(uint4*)&pooled[px * 192 + c16 * 16] = o;
    }
  }
  __syncthreads();

  const int lane = tid & 63;
  const int wave = tid >> 6;
  const int mbase = p0 + wave * 32;

  uint aoff[MF];
#pragma unroll
  for (int mf = 0; mf < MF; ++mf) {
    int px = (b == 3) ? (wave * 32 + mf * 16 + (lane & 15))
                      : (mbase + mf * 16 + (lane & 15));
    aoff[mf] = (uint)px * 192u;
  }
  const uint klane = (uint)(lane >> 4) * 16u;
  const uint blane = (uint)lane * 16u;

  i32x4 acc[MF][NFW];
#pragma unroll
  for (int i = 0; i < MF; ++i)
#pragma unroll
    for (int j = 0; j < NFW; ++j) acc[i][j] = {0, 0, 0, 0};

#pragma unroll
  for (int c = 0; c < 3; ++c) {
    i32x4 af[MF];
#pragma unroll
    for (int mf = 0; mf < MF; ++mf)
      af[mf] = (b == 3) ? *(const i32x4*)&pooled[aoff[mf] + (uint)c * 64u + klane]
                        : *(const i32x4*)(xq + (aoff[mf] + (uint)c * 64u + klane));
    i32x4 bfr[NFW];
#pragma unroll
    for (int nf = 0; nf < NFW; ++nf)
      if (nf < nfw)
        bfr[nf] = *(const i32x4*)&btile[(uint)((c * nfw + nf) * 1024) + blane];
#pragma unroll
    for (int mf = 0; mf < MF; ++mf)
#pragma unroll
      for (int nf = 0; nf < NFW; ++nf)
        if (nf < nfw)
          acc[mf][nf] = __builtin_amdgcn_mfma_i32_16x16x64_i8(af[mf], bfr[nf],
                                                              acc[mf][nf], 0, 0, 0);
  }

  conv_epilogue<NFW, MF>(acc, nfw, lane, wave, mbase, yhb, stb, 256);
}

// ---------- merged b2b + b3b + bnout(b1,b4) (blockIdx.y in 0..4) ----------
struct M2Args {
  const u16* yhin0; const double* stp0; const float* g0; const float* be0;
  const char* bp0; double* stb0; u16* yho0;   // b2b
  const u16* yhin1; const double* stp1; const float* g1; const float* be1;
  const char* bp1; double* stb1; u16* yho1;   // b3b
  const u16* yh; const double* st; float* out;
  const float* gb1; const float* beb1; const float* gb4; const float* beb4;
};

__global__ __launch_bounds__(256, 3) void cstat9m_kernel(M2Args A) {
  __shared__ __align__(16) char atile[6 * 34 * 96 + 64];  // b2b size; b3b uses prefix
  __shared__ __align__(16) char btile[6144];               // b3b only
  __shared__ float2 cfl[96];
  __shared__ float redm[4][4][16][2];                      // b2b custom epilogue

  const int tid = threadIdx.x;
  const int y = blockIdx.y;

  if (y >= 2) {
    // ---- streaming: bnout for b1 (y=2: co 0-31, y=3: co 32-63) and b4 (y=4) ----
    int lco = ((y == 3) ? 32 : 0) + (blockIdx.x >> 5);
    int chunk = blockIdx.x & 31;
    if (y == 4)
      bnout_one(A.yh + (size_t)176 * PTOT, A.st + 6 * 256 * NREP, A.gb4, A.beb4,
                A.out, 224, lco, chunk, tid);
    else
      bnout_one(A.yh, A.st, A.gb1, A.beb1, A.out, 0, lco, chunk, tid);
    return;
  }

  if (y == 0) {
    // ===== b2b: qstage(b2a) -> 3x3 96->128, 2x2 wave split, B global =====
    constexpr int CI = 96;
    constexpr int CPR = 5;
    constexpr int NCH = 15;
    constexpr int MF = 4;
    constexpr int NFW = 4;
    constexpr int TILE = 6 * 34 * CI;

    if (tid < CI) {
      double s1d = 0., s2d = 0.;
#pragma unroll
      for (int r = 0; r < NREP; ++r) {
        s1d += A.stp0[r * 256 + 2 * tid];
        s2d += A.stp0[r * 256 + 2 * tid + 1];
      }
      double m = s1d * (1.0 / PTOT);
      double v = s2d * (1.0 / PTOT) - m * m;
      double inv = 1.0 / sqrt(v + 1e-5);
      double c0 = (double)A.g0[tid] * inv;
      cfl[tid] = make_float2((float)c0, (float)((double)A.be0[tid] - m * c0));
    }
    {
      uint4 z = {0, 0, 0, 0};
      for (int s = tid * 16; s < TILE + 64; s += 4096) *(uint4*)&atile[s] = z;
    }
    __syncthreads();

    const int p0 = blockIdx.x * 128;
    const int n = p0 >> 10, h0 = (p0 & 1023) >> 5;
    for (int task = tid; task < CI * 6; task += 256) {
      int co = task / 6, rr = task - co * 6;
      int irow = h0 - 1 + rr;
      if (irow < 0 || irow > 31) continue;
      const u16* src = A.yhin0 + (size_t)co * PTOT + (n << 10) + (irow << 5);
      float2 cc = cfl[co];
      char* dst = &atile[(rr * 34 + 1) * CI + co];
#pragma unroll
      for (int w8 = 0; w8 < 4; ++w8) {
        u16x8 v = *(const u16x8*)(src + w8 * 8);
#pragma unroll
        for (int e = 0; e < 8; ++e) {
          float z = fmaxf(fmaf(bf2f(v[e]), cc.x, cc.y), 0.f);
          dst[(w8 * 8 + e) * CI] = (char)min((int)rintf(z * 128.f), 127);
        }
      }
    }
    __syncthreads();

    const int lane = tid & 63;
    const int wave = tid >> 6;
    const int pg = wave >> 1, cg = wave & 1;

    uint albase[MF];
#pragma unroll
    for (int mf = 0; mf < MF; ++mf) {
      int lp = pg * 64 + mf * 16 + (lane & 15);
      albase[mf] = (uint)((((lp >> 5) + 1) * 34 + 1 + (lp & 31)) * CI);
    }
    const uint klane = (uint)(lane >> 4) * 16u;
    const uint blane = (uint)lane * 16u;

    i32x4 acc[MF][NFW];
#pragma unroll
    for (int i = 0; i < MF; ++i)
#pragma unroll
      for (int j = 0; j < NFW; ++j) acc[i][j] = {0, 0, 0, 0};

#pragma unroll 3
    for (int c = 0; c < NCH; ++c) {
      int rr = c / CPR, o = (c - rr * CPR) * 64;
      uint koff = (uint)((rr - 1) * 34 * CI + o - CI);
      i32x4 af[MF];
#pragma unroll
      for (int mf = 0; mf < MF; ++mf)
        af[mf] = *(const i32x4*)&atile[albase[mf] + koff + klane];
      i32x4 bfr[NFW];
#pragma unroll
      for (int nf = 0; nf < NFW; ++nf)
        bfr[nf] = *(const i32x4*)(A.bp0 +
                                  ((uint)((c * 8 + cg * 4 + nf) * 1024) + blane));
#pragma unroll
      for (int mf = 0; mf < MF; ++mf)
#pragma unroll
        for (int nf = 0; nf < NFW; ++nf)
          acc[mf][nf] = __builtin_amdgcn_mfma_i32_16x16x64_i8(af[mf], bfr[nf],
                                                              acc[mf][nf], 0, 0, 0);
    }

    float yv[MF][NFW][4];
#pragma unroll
    for (int mf = 0; mf < MF; ++mf)
#pragma unroll
      for (int nf = 0; nf < NFW; ++nf) {
        int col = cg * 64 + nf * 16 + (lane & 15);
        int pix = p0 + pg * 64 + mf * 16 + ((lane >> 4) << 2);
        u16x4 o;
#pragma unroll
        for (int r = 0; r < 4; ++r) {
          float v = (float)acc[mf][nf][r] * 6.103515625e-05f;
          yv[mf][nf][r] = v;
          o[r] = bf_rne(v);
        }
        *(u16x4*)&A.yho0[(size_t)col * PTOT + pix] = o;
      }

    float s1[NFW], s2[NFW];
#pragma unroll
    for (int nf = 0; nf < NFW; ++nf) { s1[nf] = 0.f; s2[nf] = 0.f; }
#pragma unroll
    for (int mf = 0; mf < MF; ++mf)
#pragma unroll
      for (int nf = 0; nf < NFW; ++nf)
#pragma unroll
        for (int r = 0; r < 4; ++r) {
          float v = yv[mf][nf][r];
          s1[nf] += v;
          s2[nf] += v * v;
        }
#pragma unroll
    for (int m = 16; m <= 32; m <<= 1)
#pragma unroll
      for (int nf = 0; nf < NFW; ++nf) {
        s1[nf] += __shfl_xor(s1[nf], m);
        s2[nf] += __shfl_xor(s2[nf], m);
      }
    if (lane < 16)
#pragma unroll
      for (int nf = 0; nf < NFW; ++nf) {
        redm[wave][nf][lane][0] = s1[nf];
        redm[wave][nf][lane][1] = s2[nf];
      }
    __syncthreads();
    if (tid < 128) {
      int gch = tid >> 4, l = tid & 15;
      int cg2 = gch >> 2, nf = gch & 3;
      float a = redm[cg2][nf][l][0] + redm[2 + cg2][nf][l][0];
      float b = redm[cg2][nf][l][1] + redm[2 + cg2][nf][l][1];
      int rep = blockIdx.x & (NREP - 1);
      atomicAdd(&A.stb0[rep * 256 + 2 * tid], (double)a);
      atomicAdd(&A.stb0[rep * 256 + 2 * tid + 1], (double)b);
    }
  } else {
    // ===== b3b: qstage(b3a) -> 3x3 16->32, B in LDS =====
    constexpr int CI = 16;
    constexpr int NCH = 3;
    constexpr int MF = 2;
    constexpr int NFW = 2;
    constexpr int TILE = 6 * 34 * CI;

    if (tid < CI) {
      double s1d = 0., s2d = 0.;
#pragma unroll
      for (int r = 0; r < NREP; ++r) {
        s1d += A.stp1[r * 256 + 2 * tid];
        s2d += A.stp1[r * 256 + 2 * tid + 1];
      }
      double m = s1d * (1.0 / PTOT);
      double v = s2d * (1.0 / PTOT) - m * m;
      double inv = 1.0 / sqrt(v + 1e-5);
      double c0 = (double)A.g1[tid] * inv;
      cfl[tid] = make_float2((float)c0, (float)((double)A.be1[tid] - m * c0));
    }
    for (int s = tid * 16; s < 6144; s += 4096)
      *(uint4*)&btile[s] = *(const uint4*)(A.bp1 + s);
    {
      uint4 z = {0, 0, 0, 0};
      for (int s = tid * 16; s < TILE + 64; s += 4096) *(uint4*)&atile[s] = z;
    }
    __syncthreads();

    const int p0 = blockIdx.x * 128;
    const int n = p0 >> 10, h0 = (p0 & 1023) >> 5;
    for (int task = tid; task < CI * 6; task += 256) {
      int co = task / 6, rr = task - co * 6;
      int irow = h0 - 1 + rr;
      if (irow < 0 || irow > 31) continue;
      const u16* src = A.yhin1 + (size_t)co * PTOT + (n << 10) + (irow << 5);
      float2 cc = cfl[co];
      char* dst = &atile[(rr * 34 + 1) * CI + co];
#pragma unroll
      for (int w8 = 0; w8 < 4; ++w8) {
        u16x8 v = *(const u16x8*)(src + w8 * 8);
#pragma unroll
        for (int e = 0; e < 8; ++e) {
          float z = fmaxf(fmaf(bf2f(v[e]), cc.x, cc.y), 0.f);
          dst[(w8 * 8 + e) * CI] = (char)min((int)rintf(z * 128.f), 127);
        }
      }
    }
    __syncthreads();

    const int lane = tid & 63;
    const int wave = tid >> 6;
    const int mbase = blockIdx.x * 128 + wave * 32;

    uint albase[MF];
#pragma unroll
    for (int mf = 0; mf < MF; ++mf) {
      int lp = wave * 32 + mf * 16 + (lane & 15);
      albase[mf] = (uint)((((lp >> 5) + 1) * 34 + 1 + (lp & 31)) * CI);
    }
    const uint klane = (uint)(lane >> 4) * 16u;
    const uint blane = (uint)lane * 16u;

    i32x4 acc[MF][NFW];
#pragma unroll
    for (int i = 0; i < MF; ++i)
#pragma unroll
      for (int j = 0; j < NFW; ++j) acc[i][j] = {0, 0, 0, 0};

#pragma unroll
    for (int c = 0; c < NCH; ++c) {
      uint koff = (uint)((c - 1) * 34 * CI - CI);
      i32x4 af[MF];
#pragma unroll
      for (int mf = 0; mf < MF; ++mf)
        af[mf] = *(const i32x4*)&atile[albase[mf] + koff + klane];
      i32x4 bfr[NFW];
#pragma unroll
      for (int nf = 0; nf < NFW; ++nf)
        bfr[nf] = *(const i32x4*)&btile[(uint)((c * 2 + nf) * 1024) + blane];
#pragma unroll
      for (int mf = 0; mf < MF; ++mf)
#pragma unroll
        for (int nf = 0; nf < NFW; ++nf)
          acc[mf][nf] = __builtin_amdgcn_mfma_i32_16x16x64_i8(af[mf], bfr[nf],
                                                              acc[mf][nf], 0, 0, 0);
    }

    conv_epilogue<NFW, MF>(acc, NFW, lane, wave, mbase, A.yho1, A.stb1, 256);
  }
}

// ---------- b3c conv + bnout(b2b) co-dispatch (blockIdx.y in 0..4) ----------
struct M3Args {
  const u16* yhin; const double* stp; const float* gp; const float* bep;
  const char* bp; double* stb; u16* yho;       // b3c conv
  const u16* yh2b; const double* st2b; const float* g2b; const float* be2b;
  float* out;                                   // bnout b2b
};

__global__ __launch_bounds__(256, 4) void cstat9c_kernel(M3Args A) {
  constexpr int CI = 32;
  constexpr int CPR = 2;
  constexpr int NCH = 6;
  constexpr int NFW = 2;
  constexpr int MF = 2;
  constexpr int TILE = 6 * 34 * CI;

  __shared__ __align__(16) char atile[TILE + 64];
  __shared__ __align__(16) char btile[12288];
  __shared__ float2 cfl[CI];

  const int tid = threadIdx.x;
  const int y = blockIdx.y;

  if (y >= 1) {
    // ---- streaming: bnout for b2b channels 64..191 (4 slices of 32) ----
    int lco = (y - 1) * 32 + (blockIdx.x >> 5);
    int chunk = blockIdx.x & 31;
    bnout_one(A.yh2b, A.st2b, A.g2b, A.be2b, A.out, 64, lco, chunk, tid);
    return;
  }

  if (tid < CI) {
    double s1d = 0., s2d = 0.;
#pragma unroll
    for (int r = 0; r < NREP; ++r) {
      s1d += A.stp[r * 256 + 2 * tid];
      s2d += A.stp[r * 256 + 2 * tid + 1];
    }
    double m = s1d * (1.0 / PTOT);
    double v = s2d * (1.0 / PTOT) - m * m;
    double inv = 1.0 / sqrt(v + 1e-5);
    double c0 = (double)A.gp[tid] * inv;
    cfl[tid] = make_float2((float)c0, (float)((double)A.bep[tid] - m * c0));
  }
  for (int s = tid * 16; s < 12288; s += 4096)
    *(uint4*)&btile[s] = *(const uint4*)(A.bp + s);
  {
    uint4 z = {0, 0, 0, 0};
    for (int s = tid * 16; s < TILE + 64; s += 4096) *(uint4*)&atile[s] = z;
  }
  __syncthreads();

  const int p0 = blockIdx.x * 128;
  const int n = p0 >> 10, h0 = (p0 & 1023) >> 5;
  for (int task = tid; task < CI * 6; task += 256) {
    int co = task / 6, rr = task - co * 6;
    int irow = h0 - 1 + rr;
    if (irow < 0 || irow > 31) continue;
    const u16* src = A.yhin + (size_t)co * PTOT + (n << 10) + (irow << 5);
    float2 cc = cfl[co];
    char* dst = &atile[(rr * 34 + 1) * CI + co];
#pragma unroll
    for (int w8 = 0; w8 < 4; ++w8) {
      u16x8 v = *(const u16x8*)(src + w8 * 8);
#pragma unroll
      for (int e = 0; e < 8; ++e) {
        float z = fmaxf(fmaf(bf2f(v[e]), cc.x, cc.y), 0.f);
        dst[(w8 * 8 + e) * CI] = (char)min((int)rintf(z * 128.f), 127);
      }
    }
  }
  __syncthreads();

  const int lane = tid & 63;
  const int wave = tid >> 6;
  const int mbase = blockIdx.x * 128 + wave * 32;

  uint albase[MF];
#pragma unroll
  for (int mf = 0; mf < MF; ++mf) {
    int lp = wave * 32 + mf * 16 + (lane & 15);
    albase[mf] = (uint)((((lp >> 5) + 1) * 34 + 1 + (lp & 31)) * CI);
  }
  const uint klane = (uint)(lane >> 4) * 16u;
  const uint blane = (uint)lane * 16u;

  i32x4 acc[MF][NFW];
#pragma unroll
  for (int i = 0; i < MF; ++i)
#pragma unroll
    for (int j = 0; j < NFW; ++j) acc[i][j] = {0, 0, 0, 0};

#pragma unroll 2
  for (int c = 0; c < NCH; ++c) {
    int rr = c / CPR, o = (c - rr * CPR) * 64;
    uint koff = (uint)((rr - 1) * 34 * CI + o - CI);
    i32x4 af[MF];
#pragma unroll
    for (int mf = 0; mf < MF; ++mf)
      af[mf] = *(const i32x4*)&atile[albase[mf] + koff + klane];
    i32x4 bfr[NFW];
#pragma unroll
    for (int nf = 0; nf < NFW; ++nf)
      bfr[nf] = *(const i32x4*)&btile[(uint)((c * 2 + nf) * 1024) + blane];
#pragma unroll
    for (int mf = 0; mf < MF; ++mf)
#pragma unroll
      for (int nf = 0; nf < NFW; ++nf)
        acc[mf][nf] = __builtin_amdgcn_mfma_i32_16x16x64_i8(af[mf], bfr[nf],
                                                            acc[mf][nf], 0, 0, 0);
  }

  conv_epilogue<NFW, MF>(acc, NFW, lane, wave, mbase, A.yho, A.stb, 256);
}

// ---------- final: bnout for b3c channels only ----------
__global__ __launch_bounds__(256) void bnout_fin_kernel(
    const u16* __restrict__ yh, const double* __restrict__ st,
    const float* __restrict__ g, const float* __restrict__ be,
    float* __restrict__ out) {
  bnout_one(yh, st, g, be, out, 192, blockIdx.y, blockIdx.x, threadIdx.x);
}

extern "C" void kernel_launch(void* const* d_in, const int* in_sizes, int n_in,
                              void* d_out, int out_size, void* d_ws, size_t ws_size,
                              hipStream_t stream) {
  const float* x = (const float*)d_in[0];
  float* out = (float*)d_out;
  char* ws = (char*)d_ws;

  // ---- workspace layout (total 155,599,872 B) ----
  if (ws_size < 155599872ull) return;
  char* xq  = ws;                            // [PTOT][192] i8        = 25,165,824 B
  u16* yh   = (u16*)(ws + 50331648ull);      // [400][PTOT] bf16     = 104,857,600 B
  // yh slices (channel offsets): b1 0, b2a 64, b3a 160, b4 176, b2b 208,
  //                              b3b 336, b3c 368
  char* bpk = ws + 155189248ull;             // packed i8 weights        181,248 B
  double* st = (double*)(ws + 155370496ull); // 7 x NREP x 256 doubles   229,376 B

  hipMemsetAsync(st, 0, 7 * NREP * 256 * 8, stream);

  WPtrs wp;
  const int widx[7] = {1, 5, 9, 13, 17, 21, 25};
  for (int i = 0; i < 7; ++i) wp.p[i] = (const float*)d_in[widx[i]];
  wpack_kernel<<<708, 256, 0, stream>>>(wp, bpk);

  quantx_kernel<<<dim3(16, 3, 128), 256, 0, stream>>>(x, xq);

  double* stB[7];
  for (int b = 0; b < 7; ++b) stB[b] = st + (size_t)b * NREP * 256;

  // ---- merged 1x1 convs b1/b2a/b3a + fused pool+b4 ----
  cstat1x1_kernel<<<dim3(1024, 4), 256, 0, stream>>>(xq, bpk, st, yh);

  // ---- b2b + b3b convs, co-dispatched with bnout(b1) and bnout(b4) ----
  M2Args A;
  A.yhin0 = yh + (size_t)64 * PTOT;  A.stp0 = stB[1];
  A.g0 = (const float*)d_in[7];      A.be0 = (const float*)d_in[8];
  A.bp0 = bpk + 30720;               A.stb0 = stB[2];
  A.yho0 = yh + (size_t)208 * PTOT;
  A.yhin1 = yh + (size_t)160 * PTOT; A.stp1 = stB[3];
  A.g1 = (const float*)d_in[15];     A.be1 = (const float*)d_in[16];
  A.bp1 = bpk + 156672;              A.stb1 = stB[4];
  A.yho1 = yh + (size_t)336 * PTOT;
  A.yh = yh; A.st = st; A.out = out;
  A.gb1 = (const float*)d_in[3];     A.beb1 = (const float*)d_in[4];
  A.gb4 = (const float*)d_in[27];    A.beb4 = (const float*)d_in[28];
  cstat9m_kernel<<<dim3(1024, 5), 256, 0, stream>>>(A);

  // ---- b3c conv, co-dispatched with bnout(b2b 128 ch) ----
  M3Args C;
  C.yhin = yh + (size_t)336 * PTOT;  C.stp = stB[4];
  C.gp = (const float*)d_in[19];     C.bep = (const float*)d_in[20];
  C.bp = bpk + 162816;               C.stb = stB[5];
  C.yho = yh + (size_t)368 * PTOT;
  C.yh2b = yh + (size_t)208 * PTOT;  C.st2b = stB[2];
  C.g2b = (const float*)d_in[11];    C.be2b = (const float*)d_in[12];
  C.out = out;
  cstat9c_kernel<<<dim3(1024, 5), 256, 0, stream>>>(C);

  // ---- final: bnout for b3c's 32 channels ----
  bnout_fin_kernel<<<dim3(32, 32), 256, 0, stream>>>(
      yh + (size_t)368 * PTOT, stB[5], (const float*)d_in[23],
      (const float*)d_in[24], out);
}

// Round 18
// 187.886 us; speedup vs baseline: 1.0044x; 1.0044x over previous
//
#include <hip/hip_runtime.h>

typedef unsigned short u16;
typedef unsigned int u32;
typedef __attribute__((ext_vector_type(4))) int i32x4;
typedef __attribute__((ext_vector_type(4))) float f32x4;
typedef __attribute__((ext_vector_type(4))) u16 u16x4;
typedef __attribute__((ext_vector_type(8))) u16 u16x8;

#define PTOT 131072   // 128 images * 32*32 pixels
#define NREP 16       // stat accumulator replicas (atomic de-contention)

// ---------- helpers ----------
static __device__ __forceinline__ int qi8(float v) {  // round-half-even, clip +-127
  int q = (int)rintf(v * 128.f);
  return max(-127, min(127, q));
}
static __device__ __forceinline__ u16 bf_rne(float v) { // round-nearest-even bf16
  u32 u = __float_as_uint(v);
  u += 0x7fffu + ((u >> 16) & 1u);
  return (u16)(u >> 16);
}
static __device__ __forceinline__ float bf2f(u16 v) {
  return __uint_as_float((u32)v << 16);
}

// ---------- weight quantize + i8 MFMA fragment packing (row-linear K) ----------
struct WPtrs { const float* p[7]; };

__global__ void wpack_kernel(WPtrs wp, char* __restrict__ o) {
  // {byte_off, CIr, KROWP, KH, Co}   (len = NCH*NF*1024)
  static const int S[7][5] = {
      {0,      192, 192, 1, 64},   // b1   NCH=3 NF=4  12288
      {12288,  192, 192, 1, 96},   // b2a  NCH=3 NF=6  18432
      {30720,  96,  320, 3, 128},  // b2b  NCH=15 NF=8 122880
      {153600, 192, 192, 1, 16},   // b3a  NCH=3 NF=1  3072
      {156672, 16,  64,  3, 32},   // b3b  NCH=3 NF=2  6144
      {162816, 32,  128, 3, 32},   // b3c  NCH=6 NF=2  12288
      {175104, 192, 192, 1, 32},   // b4   NCH=3 NF=2  6144
  };
  int idx = blockIdx.x * 256 + threadIdx.x;
  if (idx >= 181248) return;
  int s = 0;
#pragma unroll
  for (int i = 1; i < 7; ++i)
    if (idx >= S[i][0]) s = i;
  int local = idx - S[s][0];
  int CIr = S[s][1], KROWP = S[s][2], KH = S[s][3], Co = S[s][4];
  int j = local & 15, lane = (local >> 4) & 63, f = local >> 10;
  int NF = Co >> 4;
  int c = f / NF, nf = f - c * NF;
  int co = nf * 16 + (lane & 15);
  int k = c * 64 + ((lane >> 4) << 4) + j;
  int r = k / KROWP, kk = k - r * KROWP;
  char val = 0;
  if (kk < 3 * CIr || KH == 1) {
    int kw = (KH == 1) ? 0 : (kk / CIr);
    int ci = (KH == 1) ? kk : (kk - kw * CIr);
    val = (char)qi8(wp.p[s][(((size_t)co * CIr + ci) * KH + r) * KH + kw]);
  }
  o[idx] = val;
}

// ---------- quantize x: NCHW f32 -> NHWC int8 ----------
__global__ __launch_bounds__(256) void quantx_kernel(const float* __restrict__ x,
                                                     char* __restrict__ xq) {
  __shared__ __align__(16) char tile[64][80];
  int n = blockIdx.z, hwb = blockIdx.x * 64, cb = blockIdx.y * 64;
  int lane = threadIdx.x & 63, sub = threadIdx.x >> 6;
#pragma unroll
  for (int i = 0; i < 16; ++i) {
    int c = sub + i * 4;
    float v = x[(((size_t)n * 192 + cb + c) << 10) + hwb + lane];
    tile[lane][c] = (char)qi8(v);
  }
  __syncthreads();
  int t = threadIdx.x, px = t >> 2, c16 = t & 3;
  uint4 v = *(const uint4*)&tile[px][c16 * 16];
  *(uint4*)&xq[(((size_t)n << 10) + hwb + px) * 192 + cb + c16 * 16] = v;
}

// ---------- one channel-chunk of BN+ReLU apply -> f32 NCHW out ----------
static __device__ __forceinline__ void bnout_one(
    const u16* __restrict__ yhbase, const double* __restrict__ stb,
    const float* __restrict__ g, const float* __restrict__ be,
    float* __restrict__ out, int cog, int lco, int chunk, int tid) {
  double s1d = 0., s2d = 0.;
#pragma unroll
  for (int r = 0; r < NREP; ++r) {
    s1d += stb[r * 256 + 2 * lco];
    s2d += stb[r * 256 + 2 * lco + 1];
  }
  double m = s1d * (1.0 / PTOT);
  double v = s2d * (1.0 / PTOT) - m * m;
  double inv = 1.0 / sqrt(v + 1e-5);
  double c0d = (double)g[lco] * inv;
  float c0 = (float)c0d;
  float c1 = (float)((double)be[lco] - m * c0d);

  int p0 = chunk * 4096 + tid * 16;
  int n = p0 >> 10, hw = p0 & 1023;
  const u16* yp = yhbase + (size_t)lco * PTOT + p0;
  float* op = out + (((size_t)(n * 256 + cog + lco)) << 10) + hw;
#pragma unroll
  for (int half = 0; half < 2; ++half) {
    u16x8 r = *(const u16x8*)(yp + half * 8);
    f32x4 a, b;
#pragma unroll
    for (int e = 0; e < 4; ++e) {
      a[e] = fmaxf(fmaf(bf2f(r[e]), c0, c1), 0.f);
      b[e] = fmaxf(fmaf(bf2f(r[e + 4]), c0, c1), 0.f);
    }
    *(f32x4*)(op + half * 8) = a;
    *(f32x4*)(op + half * 8 + 4) = b;
  }
}

// ---------- vectorized qstage: BN+ReLU+quantize yh -> LDS i8 tile ----------
// task = (co-quad, row rr, 8-px group w8); composes 4 channel-bytes per pixel
// into one u32 (values in [0,127] after ReLU -> plain OR-pack), 8 ds_write_b32
// per task instead of 32 byte-writes. Values identical to the scalar path.
template <int CI>
static __device__ __forceinline__ void qstage4(
    const u16* __restrict__ yhin, const float2* cfl, char* atile,
    int n, int h0, int tid) {
  for (int task = tid; task < (CI / 4) * 24; task += 256) {
    int co4 = task / 24, rem = task - co4 * 24;
    int rr = rem >> 2, w8 = rem & 3;
    int irow = h0 - 1 + rr;
    if (irow < 0 || irow > 31) continue;
    const u16* src = yhin + (size_t)(co4 * 4) * PTOT + (n << 10) + (irow << 5) + w8 * 8;
    u16x8 v0 = *(const u16x8*)(src);
    u16x8 v1 = *(const u16x8*)(src + PTOT);
    u16x8 v2 = *(const u16x8*)(src + 2 * (size_t)PTOT);
    u16x8 v3 = *(const u16x8*)(src + 3 * (size_t)PTOT);
    float2 c0 = cfl[co4 * 4], c1 = cfl[co4 * 4 + 1];
    float2 c2 = cfl[co4 * 4 + 2], c3 = cfl[co4 * 4 + 3];
    u32* dst = (u32*)&atile[(rr * 34 + 1 + w8 * 8) * CI + co4 * 4];
#pragma unroll
    for (int w = 0; w < 8; ++w) {
      u32 q0 = (u32)min((int)rintf(fmaxf(fmaf(bf2f(v0[w]), c0.x, c0.y), 0.f) * 128.f), 127);
      u32 q1 = (u32)min((int)rintf(fmaxf(fmaf(bf2f(v1[w]), c1.x, c1.y), 0.f) * 128.f), 127);
      u32 q2 = (u32)min((int)rintf(fmaxf(fmaf(bf2f(v2[w]), c2.x, c2.y), 0.f) * 128.f), 127);
      u32 q3 = (u32)min((int)rintf(fmaxf(fmaf(bf2f(v3[w]), c3.x, c3.y), 0.f) * 128.f), 127);
      dst[w * (CI / 4)] = q0 | (q1 << 8) | (q2 << 16) | (q3 << 24);
    }
  }
}

// ---------- shared conv epilogue (runtime nfw guard) ----------
template <int NFW, int MF>
static __device__ __forceinline__ void conv_epilogue(
    i32x4 (&acc)[MF][NFW], int nfw, int lane, int wave, int mbase,
    u16* __restrict__ yh, double* __restrict__ stb, int ststride) {
  float yv[MF][NFW][4];
#pragma unroll
  for (int mf = 0; mf < MF; ++mf)
#pragma unroll
    for (int nf = 0; nf < NFW; ++nf)
      if (nf < nfw) {
        int col = nf * 16 + (lane & 15);
        int pix = mbase + mf * 16 + ((lane >> 4) << 2);
        u16x4 o;
#pragma unroll
        for (int r = 0; r < 4; ++r) {
          float v = (float)acc[mf][nf][r] * 6.103515625e-05f;  // 2^-14 (exact)
          yv[mf][nf][r] = v;
          o[r] = bf_rne(v);
        }
        *(u16x4*)&yh[(size_t)col * PTOT + pix] = o;
      }

  float s1[NFW], s2[NFW];
#pragma unroll
  for (int nf = 0; nf < NFW; ++nf) { s1[nf] = 0.f; s2[nf] = 0.f; }
#pragma unroll
  for (int mf = 0; mf < MF; ++mf)
#pragma unroll
    for (int nf = 0; nf < NFW; ++nf)
      if (nf < nfw)
#pragma unroll
        for (int r = 0; r < 4; ++r) {
          float v = yv[mf][nf][r];
          s1[nf] += v;
          s2[nf] += v * v;
        }
#pragma unroll
  for (int m = 16; m <= 32; m <<= 1)
#pragma unroll
    for (int nf = 0; nf < NFW; ++nf) {
      s1[nf] += __shfl_xor(s1[nf], m);
      s2[nf] += __shfl_xor(s2[nf], m);
    }
  __shared__ float red[4][NFW][16][2];
  if (lane < 16)
#pragma unroll
    for (int nf = 0; nf < NFW; ++nf) {
      red[wave][nf][lane][0] = s1[nf];
      red[wave][nf][lane][1] = s2[nf];
    }
  __syncthreads();
  const int t = threadIdx.x;
  if (t < 16 * nfw) {
    int nf = t >> 4, l = t & 15;
    float a = red[0][nf][l][0] + red[1][nf][l][0] + red[2][nf][l][0] + red[3][nf][l][0];
    float b = red[0][nf][l][1] + red[1][nf][l][1] + red[2][nf][l][1] + red[3][nf][l][1];
    int rep = blockIdx.x & (NREP - 1);
    atomicAdd(&stb[rep * ststride + 2 * t], (double)a);
    atomicAdd(&stb[rep * ststride + 2 * t + 1], (double)b);
  }
}

// ---------- merged 1x1 convs {b1,b2a,b3a} + fused pool+b4 (blockIdx.y=3) ----------
__global__ __launch_bounds__(256, 4) void cstat1x1_kernel(
    const char* __restrict__ xq, const char* __restrict__ bpk,
    double* __restrict__ st, u16* __restrict__ yh) {
  constexpr int NFW = 6;
  constexpr int MF = 2;
  __shared__ __align__(16) char smem[30720];

  const int b = blockIdx.y;  // uniform
  const int nfw = (b == 0) ? 4 : (b == 1) ? 6 : (b == 2) ? 1 : 2;
  const int bpo = (b == 0) ? 0 : (b == 1) ? 12288 : (b == 2) ? 153600 : 175104;
  const int sto = (b == 0) ? 0 : (b == 1) ? 256 * NREP
                           : (b == 2) ? 3 * 256 * NREP : 6 * 256 * NREP;
  const int yho = (b == 0) ? 0 : (b == 1) ? 64 : (b == 2) ? 160 : 176;
  const char* bp = bpk + bpo;
  double* stb = st + sto;
  u16* yhb = yh + (size_t)yho * PTOT;

  const int tid = threadIdx.x;
  char* btile = smem;
  char* pooled = smem + 6144;
  const int bsz = nfw * 3 * 1024;
  for (int s = tid * 16; s < bsz; s += 4096)
    *(uint4*)&btile[s] = *(const uint4*)(bp + s);

  const int p0 = blockIdx.x * 128;
  if (b == 3) {  // build pooled tile (identical clamped 3x3 max over xq)
    const int n = p0 >> 10, h0 = (p0 & 1023) >> 5;
    for (int task = tid; task < 128 * 12; task += 256) {
      int px = task / 12, c16 = task - px * 12;
      int h = h0 + (px >> 5), w = px & 31;
      int m[16];
#pragma unroll
      for (int j = 0; j < 16; ++j) m[j] = -127;
      for (int dh = -1; dh <= 1; ++dh) {
        int hh = h + dh; if (hh < 0 || hh > 31) continue;
        for (int dw = -1; dw <= 1; ++dw) {
          int ww = w + dw; if (ww < 0 || ww > 31) continue;
          uint4 v = *(const uint4*)&xq[((size_t)((n << 10) + (hh << 5) + ww)) * 192 +
                                       c16 * 16];
          const char* bb = reinterpret_cast<const char*>(&v);
#pragma unroll
          for (int t = 0; t < 16; ++t) {
            int bv = (int)bb[t];
            m[t] = bv > m[t] ? bv : m[t];
          }
        }
      }
      uint4 o;
      char* ob = reinterpret_cast<char*>(&o);
#pragma unroll
      for (int t = 0; t < 16; ++t) ob[t] = (char)m[t];
      *(uint4*)&pooled[px * 192 + c16 * 16] = o;
    }
  }
  __syncthreads();

  const int lane = tid & 63;
  const int wave = tid >> 6;
  const int mbase = p0 + wave * 32;

  uint aoff[MF];
#pragma unroll
  for (int mf = 0; mf < MF; ++mf) {
    int px = (b == 3) ? (wave * 32 + mf * 16 + (lane & 15))
                      : (mbase + mf * 16 + (lane & 15));
    aoff[mf] = (uint)px * 192u;
  }
  const uint klane = (uint)(lane >> 4) * 16u;
  const uint blane = (uint)lane * 16u;

  i32x4 acc[MF][NFW];
#pragma unroll
  for (int i = 0; i < MF; ++i)
#pragma unroll
    for (int j = 0; j < NFW; ++j) acc[i][j] = {0, 0, 0, 0};

#pragma unroll
  for (int c = 0; c < 3; ++c) {
    i32x4 af[MF];
#pragma unroll
    for (int mf = 0; mf < MF; ++mf)
      af[mf] = (b == 3) ? *(const i32x4*)&pooled[aoff[mf] + (uint)c * 64u + klane]
                        : *(const i32x4*)(xq + (aoff[mf] + (uint)c * 64u + klane));
    i32x4 bfr[NFW];
#pragma unroll
    for (int nf = 0; nf < NFW; ++nf)
      if (nf < nfw)
        bfr[nf] = *(const i32x4*)&btile[(uint)((c * nfw + nf) * 1024) + blane];
#pragma unroll
    for (int mf = 0; mf < MF; ++mf)
#pragma unroll
      for (int nf = 0; nf < NFW; ++nf)
        if (nf < nfw)
          acc[mf][nf] = __builtin_amdgcn_mfma_i32_16x16x64_i8(af[mf], bfr[nf],
                                                              acc[mf][nf], 0, 0, 0);
  }

  conv_epilogue<NFW, MF>(acc, nfw, lane, wave, mbase, yhb, stb, 256);
}

// ---------- merged b2b + b3b + bnout(b1,b4) (blockIdx.y in 0..4) ----------
struct M2Args {
  const u16* yhin0; const double* stp0; const float* g0; const float* be0;
  const char* bp0; double* stb0; u16* yho0;   // b2b
  const u16* yhin1; const double* stp1; const float* g1; const float* be1;
  const char* bp1; double* stb1; u16* yho1;   // b3b
  const u16* yh; const double* st; float* out;
  const float* gb1; const float* beb1; const float* gb4; const float* beb4;
};

__global__ __launch_bounds__(256, 4) void cstat9m_kernel(M2Args A) {
  __shared__ __align__(16) char atile[6 * 34 * 96 + 64];  // b2b size; b3b uses prefix
  __shared__ __align__(16) char btile[6144];               // b3b only
  __shared__ float2 cfl[96];
  __shared__ float redm[4][4][16][2];                      // b2b custom epilogue

  const int tid = threadIdx.x;
  const int y = blockIdx.y;

  if (y >= 2) {
    // ---- streaming: bnout for b1 (y=2: co 0-31, y=3: co 32-63) and b4 (y=4) ----
    int lco = ((y == 3) ? 32 : 0) + (blockIdx.x >> 5);
    int chunk = blockIdx.x & 31;
    if (y == 4)
      bnout_one(A.yh + (size_t)176 * PTOT, A.st + 6 * 256 * NREP, A.gb4, A.beb4,
                A.out, 224, lco, chunk, tid);
    else
      bnout_one(A.yh, A.st, A.gb1, A.beb1, A.out, 0, lco, chunk, tid);
    return;
  }

  if (y == 0) {
    // ===== b2b: qstage(b2a) -> 3x3 96->128, 2x2 wave split, B global =====
    constexpr int CI = 96;
    constexpr int CPR = 5;
    constexpr int NCH = 15;
    constexpr int MF = 4;
    constexpr int NFW = 4;
    constexpr int TILE = 6 * 34 * CI;

    if (tid < CI) {
      double s1d = 0., s2d = 0.;
#pragma unroll
      for (int r = 0; r < NREP; ++r) {
        s1d += A.stp0[r * 256 + 2 * tid];
        s2d += A.stp0[r * 256 + 2 * tid + 1];
      }
      double m = s1d * (1.0 / PTOT);
      double v = s2d * (1.0 / PTOT) - m * m;
      double inv = 1.0 / sqrt(v + 1e-5);
      double c0 = (double)A.g0[tid] * inv;
      cfl[tid] = make_float2((float)c0, (float)((double)A.be0[tid] - m * c0));
    }
    {
      uint4 z = {0, 0, 0, 0};
      for (int s = tid * 16; s < TILE + 64; s += 4096) *(uint4*)&atile[s] = z;
    }
    __syncthreads();

    const int p0 = blockIdx.x * 128;
    const int n = p0 >> 10, h0 = (p0 & 1023) >> 5;
    qstage4<CI>(A.yhin0, cfl, atile, n, h0, tid);
    __syncthreads();

    const int lane = tid & 63;
    const int wave = tid >> 6;
    const int pg = wave >> 1, cg = wave & 1;

    uint albase[MF];
#pragma unroll
    for (int mf = 0; mf < MF; ++mf) {
      int lp = pg * 64 + mf * 16 + (lane & 15);
      albase[mf] = (uint)((((lp >> 5) + 1) * 34 + 1 + (lp & 31)) * CI);
    }
    const uint klane = (uint)(lane >> 4) * 16u;
    const uint blane = (uint)lane * 16u;

    i32x4 acc[MF][NFW];
#pragma unroll
    for (int i = 0; i < MF; ++i)
#pragma unroll
      for (int j = 0; j < NFW; ++j) acc[i][j] = {0, 0, 0, 0};

#pragma unroll 3
    for (int c = 0; c < NCH; ++c) {
      int rr = c / CPR, o = (c - rr * CPR) * 64;
      uint koff = (uint)((rr - 1) * 34 * CI + o - CI);
      i32x4 af[MF];
#pragma unroll
      for (int mf = 0; mf < MF; ++mf)
        af[mf] = *(const i32x4*)&atile[albase[mf] + koff + klane];
      i32x4 bfr[NFW];
#pragma unroll
      for (int nf = 0; nf < NFW; ++nf)
        bfr[nf] = *(const i32x4*)(A.bp0 +
                                  ((uint)((c * 8 + cg * 4 + nf) * 1024) + blane));
#pragma unroll
      for (int mf = 0; mf < MF; ++mf)
#pragma unroll
        for (int nf = 0; nf < NFW; ++nf)
          acc[mf][nf] = __builtin_amdgcn_mfma_i32_16x16x64_i8(af[mf], bfr[nf],
                                                              acc[mf][nf], 0, 0, 0);
    }

    float yv[MF][NFW][4];
#pragma unroll
    for (int mf = 0; mf < MF; ++mf)
#pragma unroll
      for (int nf = 0; nf < NFW; ++nf) {
        int col = cg * 64 + nf * 16 + (lane & 15);
        int pix = p0 + pg * 64 + mf * 16 + ((lane >> 4) << 2);
        u16x4 o;
#pragma unroll
        for (int r = 0; r < 4; ++r) {
          float v = (float)acc[mf][nf][r] * 6.103515625e-05f;
          yv[mf][nf][r] = v;
          o[r] = bf_rne(v);
        }
        *(u16x4*)&A.yho0[(size_t)col * PTOT + pix] = o;
      }

    float s1[NFW], s2[NFW];
#pragma unroll
    for (int nf = 0; nf < NFW; ++nf) { s1[nf] = 0.f; s2[nf] = 0.f; }
#pragma unroll
    for (int mf = 0; mf < MF; ++mf)
#pragma unroll
      for (int nf = 0; nf < NFW; ++nf)
#pragma unroll
        for (int r = 0; r < 4; ++r) {
          float v = yv[mf][nf][r];
          s1[nf] += v;
          s2[nf] += v * v;
        }
#pragma unroll
    for (int m = 16; m <= 32; m <<= 1)
#pragma unroll
      for (int nf = 0; nf < NFW; ++nf) {
        s1[nf] += __shfl_xor(s1[nf], m);
        s2[nf] += __shfl_xor(s2[nf], m);
      }
    if (lane < 16)
#pragma unroll
      for (int nf = 0; nf < NFW; ++nf) {
        redm[wave][nf][lane][0] = s1[nf];
        redm[wave][nf][lane][1] = s2[nf];
      }
    __syncthreads();
    if (tid < 128) {
      int gch = tid >> 4, l = tid & 15;
      int cg2 = gch >> 2, nf = gch & 3;
      float a = redm[cg2][nf][l][0] + redm[2 + cg2][nf][l][0];
      float b = redm[cg2][nf][l][1] + redm[2 + cg2][nf][l][1];
      int rep = blockIdx.x & (NREP - 1);
      atomicAdd(&A.stb0[rep * 256 + 2 * tid], (double)a);
      atomicAdd(&A.stb0[rep * 256 + 2 * tid + 1], (double)b);
    }
  } else {
    // ===== b3b: qstage(b3a) -> 3x3 16->32, B in LDS =====
    constexpr int CI = 16;
    constexpr int NCH = 3;
    constexpr int MF = 2;
    constexpr int NFW = 2;
    constexpr int TILE = 6 * 34 * CI;

    if (tid < CI) {
      double s1d = 0., s2d = 0.;
#pragma unroll
      for (int r = 0; r < NREP; ++r) {
        s1d += A.stp1[r * 256 + 2 * tid];
        s2d += A.stp1[r * 256 + 2 * tid + 1];
      }
      double m = s1d * (1.0 / PTOT);
      double v = s2d * (1.0 / PTOT) - m * m;
      double inv = 1.0 / sqrt(v + 1e-5);
      double c0 = (double)A.g1[tid] * inv;
      cfl[tid] = make_float2((float)c0, (float)((double)A.be1[tid] - m * c0));
    }
    for (int s = tid * 16; s < 6144; s += 4096)
      *(uint4*)&btile[s] = *(const uint4*)(A.bp1 + s);
    {
      uint4 z = {0, 0, 0, 0};
      for (int s = tid * 16; s < TILE + 64; s += 4096) *(uint4*)&atile[s] = z;
    }
    __syncthreads();

    const int p0 = blockIdx.x * 128;
    const int n = p0 >> 10, h0 = (p0 & 1023) >> 5;
    qstage4<CI>(A.yhin1, cfl, atile, n, h0, tid);
    __syncthreads();

    const int lane = tid & 63;
    const int wave = tid >> 6;
    const int mbase = blockIdx.x * 128 + wave * 32;

    uint albase[MF];
#pragma unroll
    for (int mf = 0; mf < MF; ++mf) {
      int lp = wave * 32 + mf * 16 + (lane & 15);
      albase[mf] = (uint)((((lp >> 5) + 1) * 34 + 1 + (lp & 31)) * CI);
    }
    const uint klane = (uint)(lane >> 4) * 16u;
    const uint blane = (uint)lane * 16u;

    i32x4 acc[MF][NFW];
#pragma unroll
    for (int i = 0; i < MF; ++i)
#pragma unroll
      for (int j = 0; j < NFW; ++j) acc[i][j] = {0, 0, 0, 0};

#pragma unroll
    for (int c = 0; c < NCH; ++c) {
      uint koff = (uint)((c - 1) * 34 * CI - CI);
      i32x4 af[MF];
#pragma unroll
      for (int mf = 0; mf < MF; ++mf)
        af[mf] = *(const i32x4*)&atile[albase[mf] + koff + klane];
      i32x4 bfr[NFW];
#pragma unroll
      for (int nf = 0; nf < NFW; ++nf)
        bfr[nf] = *(const i32x4*)&btile[(uint)((c * 2 + nf) * 1024) + blane];
#pragma unroll
      for (int mf = 0; mf < MF; ++mf)
#pragma unroll
        for (int nf = 0; nf < NFW; ++nf)
          acc[mf][nf] = __builtin_amdgcn_mfma_i32_16x16x64_i8(af[mf], bfr[nf],
                                                              acc[mf][nf], 0, 0, 0);
    }

    conv_epilogue<NFW, MF>(acc, NFW, lane, wave, mbase, A.yho1, A.stb1, 256);
  }
}

// ---------- b3c conv + bnout(b2b) co-dispatch (blockIdx.y in 0..4) ----------
struct M3Args {
  const u16* yhin; const double* stp; const float* gp; const float* bep;
  const char* bp; double* stb; u16* yho;       // b3c conv
  const u16* yh2b; const double* st2b; const float* g2b; const float* be2b;
  float* out;                                   // bnout b2b
};

__global__ __launch_bounds__(256, 4) void cstat9c_kernel(M3Args A) {
  constexpr int CI = 32;
  constexpr int CPR = 2;
  constexpr int NCH = 6;
  constexpr int NFW = 2;
  constexpr int MF = 2;
  constexpr int TILE = 6 * 34 * CI;

  __shared__ __align__(16) char atile[TILE + 64];
  __shared__ __align__(16) char btile[12288];
  __shared__ float2 cfl[CI];

  const int tid = threadIdx.x;
  const int y = blockIdx.y;

  if (y >= 1) {
    // ---- streaming: bnout for b2b channels 64..191 (4 slices of 32) ----
    int lco = (y - 1) * 32 + (blockIdx.x >> 5);
    int chunk = blockIdx.x & 31;
    bnout_one(A.yh2b, A.st2b, A.g2b, A.be2b, A.out, 64, lco, chunk, tid);
    return;
  }

  if (tid < CI) {
    double s1d = 0., s2d = 0.;
#pragma unroll
    for (int r = 0; r < NREP; ++r) {
      s1d += A.stp[r * 256 + 2 * tid];
      s2d += A.stp[r * 256 + 2 * tid + 1];
    }
    double m = s1d * (1.0 / PTOT);
    double v = s2d * (1.0 / PTOT) - m * m;
    double inv = 1.0 / sqrt(v + 1e-5);
    double c0 = (double)A.gp[tid] * inv;
    cfl[tid] = make_float2((float)c0, (float)((double)A.bep[tid] - m * c0));
  }
  for (int s = tid * 16; s < 12288; s += 4096)
    *(uint4*)&btile[s] = *(const uint4*)(A.bp + s);
  {
    uint4 z = {0, 0, 0, 0};
    for (int s = tid * 16; s < TILE + 64; s += 4096) *(uint4*)&atile[s] = z;
  }
  __syncthreads();

  const int p0 = blockIdx.x * 128;
  const int n = p0 >> 10, h0 = (p0 & 1023) >> 5;
  qstage4<CI>(A.yhin, cfl, atile, n, h0, tid);
  __syncthreads();

  const int lane = tid & 63;
  const int wave = tid >> 6;
  const int mbase = blockIdx.x * 128 + wave * 32;

  uint albase[MF];
#pragma unroll
  for (int mf = 0; mf < MF; ++mf) {
    int lp = wave * 32 + mf * 16 + (lane & 15);
    albase[mf] = (uint)((((lp >> 5) + 1) * 34 + 1 + (lp & 31)) * CI);
  }
  const uint klane = (uint)(lane >> 4) * 16u;
  const uint blane = (uint)lane * 16u;

  i32x4 acc[MF][NFW];
#pragma unroll
  for (int i = 0; i < MF; ++i)
#pragma unroll
    for (int j = 0; j < NFW; ++j) acc[i][j] = {0, 0, 0, 0};

#pragma unroll 2
  for (int c = 0; c < NCH; ++c) {
    int rr = c / CPR, o = (c - rr * CPR) * 64;
    uint koff = (uint)((rr - 1) * 34 * CI + o - CI);
    i32x4 af[MF];
#pragma unroll
    for (int mf = 0; mf < MF; ++mf)
      af[mf] = *(const i32x4*)&atile[albase[mf] + koff + klane];
    i32x4 bfr[NFW];
#pragma unroll
    for (int nf = 0; nf < NFW; ++nf)
      bfr[nf] = *(const i32x4*)&btile[(uint)((c * 2 + nf) * 1024) + blane];
#pragma unroll
    for (int mf = 0; mf < MF; ++mf)
#pragma unroll
      for (int nf = 0; nf < NFW; ++nf)
        acc[mf][nf] = __builtin_amdgcn_mfma_i32_16x16x64_i8(af[mf], bfr[nf],
                                                            acc[mf][nf], 0, 0, 0);
  }

  conv_epilogue<NFW, MF>(acc, NFW, lane, wave, mbase, A.yho, A.stb, 256);
}

// ---------- final: bnout for b3c channels only ----------
__global__ __launch_bounds__(256) void bnout_fin_kernel(
    const u16* __restrict__ yh, const double* __restrict__ st,
    const float* __restrict__ g, const float* __restrict__ be,
    float* __restrict__ out) {
  bnout_one(yh, st, g, be, out, 192, blockIdx.y, blockIdx.x, threadIdx.x);
}

extern "C" void kernel_launch(void* const* d_in, const int* in_sizes, int n_in,
                              void* d_out, int out_size, void* d_ws, size_t ws_size,
                              hipStream_t stream) {
  const float* x = (const float*)d_in[0];
  float* out = (float*)d_out;
  char* ws = (char*)d_ws;

  // ---- workspace layout (total 155,599,872 B) ----
  if (ws_size < 155599872ull) return;
  char* xq  = ws;                            // [PTOT][192] i8        = 25,165,824 B
  u16* yh   = (u16*)(ws + 50331648ull);      // [400][PTOT] bf16     = 104,857,600 B
  // yh slices (channel offsets): b1 0, b2a 64, b3a 160, b4 176, b2b 208,
  //                              b3b 336, b3c 368
  char* bpk = ws + 155189248ull;             // packed i8 weights        181,248 B
  double* st = (double*)(ws + 155370496ull); // 7 x NREP x 256 doubles   229,376 B

  hipMemsetAsync(st, 0, 7 * NREP * 256 * 8, stream);

  WPtrs wp;
  const int widx[7] = {1, 5, 9, 13, 17, 21, 25};
  for (int i = 0; i < 7; ++i) wp.p[i] = (const float*)d_in[widx[i]];
  wpack_kernel<<<708, 256, 0, stream>>>(wp, bpk);

  quantx_kernel<<<dim3(16, 3, 128), 256, 0, stream>>>(x, xq);

  double* stB[7];
  for (int b = 0; b < 7; ++b) stB[b] = st + (size_t)b * NREP * 256;

  // ---- merged 1x1 convs b1/b2a/b3a + fused pool+b4 ----
  cstat1x1_kernel<<<dim3(1024, 4), 256, 0, stream>>>(xq, bpk, st, yh);

  // ---- b2b + b3b convs, co-dispatched with bnout(b1) and bnout(b4) ----
  M2Args A;
  A.yhin0 = yh + (size_t)64 * PTOT;  A.stp0 = stB[1];
  A.g0 = (const float*)d_in[7];      A.be0 = (const float*)d_in[8];
  A.bp0 = bpk + 30720;               A.stb0 = stB[2];
  A.yho0 = yh + (size_t)208 * PTOT;
  A.yhin1 = yh + (size_t)160 * PTOT; A.stp1 = stB[3];
  A.g1 = (const float*)d_in[15];     A.be1 = (const float*)d_in[16];
  A.bp1 = bpk + 156672;              A.stb1 = stB[4];
  A.yho1 = yh + (size_t)336 * PTOT;
  A.yh = yh; A.st = st; A.out = out;
  A.gb1 = (const float*)d_in[3];     A.beb1 = (const float*)d_in[4];
  A.gb4 = (const float*)d_in[27];    A.beb4 = (const float*)d_in[28];
  cstat9m_kernel<<<dim3(1024, 5), 256, 0, stream>>>(A);

  // ---- b3c conv, co-dispatched with bnout(b2b 128 ch) ----
  M3Args C;
  C.yhin = yh + (size_t)336 * PTOT;  C.stp = stB[4];
  C.gp = (const float*)d_in[19];     C.bep = (const float*)d_in[20];
  C.bp = bpk + 162816;               C.stb = stB[5];
  C.yho = yh + (size_t)368 * PTOT;
  C.yh2b = yh + (size_t)208 * PTOT;  C.st2b = stB[2];
  C.g2b = (const float*)d_in[11];    C.be2b = (const float*)d_in[12];
  C.out = out;
  cstat9c_kernel<<<dim3(1024, 5), 256, 0, stream>>>(C);

  // ---- final: bnout for b3c's 32 channels ----
  bnout_fin_kernel<<<dim3(32, 32), 256, 0, stream>>>(
      yh + (size_t)368 * PTOT, stB[5], (const float*)d_in[23],
      (const float*)d_in[24], out);
}

// Round 19
// 186.461 us; speedup vs baseline: 1.0121x; 1.0076x over previous
//
#include <hip/hip_runtime.h>

typedef unsigned short u16;
typedef unsigned int u32;
typedef __attribute__((ext_vector_type(4))) int i32x4;
typedef __attribute__((ext_vector_type(4))) float f32x4;
typedef __attribute__((ext_vector_type(4))) u16 u16x4;
typedef __attribute__((ext_vector_type(8))) u16 u16x8;

#define PTOT 131072   // 128 images * 32*32 pixels
#define NREP 16       // stat accumulator replicas (atomic de-contention)

// ---------- helpers ----------
static __device__ __forceinline__ int qi8(float v) {  // round-half-even, clip +-127
  int q = (int)rintf(v * 128.f);
  return max(-127, min(127, q));
}
static __device__ __forceinline__ u16 bf_rne(float v) { // round-nearest-even bf16
  u32 u = __float_as_uint(v);
  u += 0x7fffu + ((u >> 16) & 1u);
  return (u16)(u >> 16);
}
static __device__ __forceinline__ float bf2f(u16 v) {
  return __uint_as_float((u32)v << 16);
}

// ---------- weight quantize + i8 MFMA fragment packing (row-linear K) ----------
struct WPtrs { const float* p[7]; };

__global__ void wpack_kernel(WPtrs wp, char* __restrict__ o) {
  // {byte_off, CIr, KROWP, KH, Co}   (len = NCH*NF*1024)
  static const int S[7][5] = {
      {0,      192, 192, 1, 64},   // b1   NCH=3 NF=4  12288
      {12288,  192, 192, 1, 96},   // b2a  NCH=3 NF=6  18432
      {30720,  96,  320, 3, 128},  // b2b  NCH=15 NF=8 122880
      {153600, 192, 192, 1, 16},   // b3a  NCH=3 NF=1  3072
      {156672, 16,  64,  3, 32},   // b3b  NCH=3 NF=2  6144
      {162816, 32,  128, 3, 32},   // b3c  NCH=6 NF=2  12288
      {175104, 192, 192, 1, 32},   // b4   NCH=3 NF=2  6144
  };
  int idx = blockIdx.x * 256 + threadIdx.x;
  if (idx >= 181248) return;
  int s = 0;
#pragma unroll
  for (int i = 1; i < 7; ++i)
    if (idx >= S[i][0]) s = i;
  int local = idx - S[s][0];
  int CIr = S[s][1], KROWP = S[s][2], KH = S[s][3], Co = S[s][4];
  int j = local & 15, lane = (local >> 4) & 63, f = local >> 10;
  int NF = Co >> 4;
  int c = f / NF, nf = f - c * NF;
  int co = nf * 16 + (lane & 15);
  int k = c * 64 + ((lane >> 4) << 4) + j;
  int r = k / KROWP, kk = k - r * KROWP;
  char val = 0;
  if (kk < 3 * CIr || KH == 1) {
    int kw = (KH == 1) ? 0 : (kk / CIr);
    int ci = (KH == 1) ? kk : (kk - kw * CIr);
    val = (char)qi8(wp.p[s][(((size_t)co * CIr + ci) * KH + r) * KH + kw]);
  }
  o[idx] = val;
}

// ---------- quantize x: NCHW f32 -> NHWC int8 ----------
__global__ __launch_bounds__(256) void quantx_kernel(const float* __restrict__ x,
                                                     char* __restrict__ xq) {
  __shared__ __align__(16) char tile[64][80];
  int n = blockIdx.z, hwb = blockIdx.x * 64, cb = blockIdx.y * 64;
  int lane = threadIdx.x & 63, sub = threadIdx.x >> 6;
#pragma unroll
  for (int i = 0; i < 16; ++i) {
    int c = sub + i * 4;
    float v = x[(((size_t)n * 192 + cb + c) << 10) + hwb + lane];
    tile[lane][c] = (char)qi8(v);
  }
  __syncthreads();
  int t = threadIdx.x, px = t >> 2, c16 = t & 3;
  uint4 v = *(const uint4*)&tile[px][c16 * 16];
  *(uint4*)&xq[(((size_t)n << 10) + hwb + px) * 192 + cb + c16 * 16] = v;
}

// ---------- one channel-chunk of BN+ReLU apply -> f32 NCHW out ----------
static __device__ __forceinline__ void bnout_one(
    const u16* __restrict__ yhbase, const double* __restrict__ stb,
    const float* __restrict__ g, const float* __restrict__ be,
    float* __restrict__ out, int cog, int lco, int chunk, int tid) {
  double s1d = 0., s2d = 0.;
#pragma unroll
  for (int r = 0; r < NREP; ++r) {
    s1d += stb[r * 256 + 2 * lco];
    s2d += stb[r * 256 + 2 * lco + 1];
  }
  double m = s1d * (1.0 / PTOT);
  double v = s2d * (1.0 / PTOT) - m * m;
  double inv = 1.0 / sqrt(v + 1e-5);
  double c0d = (double)g[lco] * inv;
  float c0 = (float)c0d;
  float c1 = (float)((double)be[lco] - m * c0d);

  int p0 = chunk * 4096 + tid * 16;
  int n = p0 >> 10, hw = p0 & 1023;
  const u16* yp = yhbase + (size_t)lco * PTOT + p0;
  float* op = out + (((size_t)(n * 256 + cog + lco)) << 10) + hw;
#pragma unroll
  for (int half = 0; half < 2; ++half) {
    u16x8 r = *(const u16x8*)(yp + half * 8);
    f32x4 a, b;
#pragma unroll
    for (int e = 0; e < 4; ++e) {
      a[e] = fmaxf(fmaf(bf2f(r[e]), c0, c1), 0.f);
      b[e] = fmaxf(fmaf(bf2f(r[e + 4]), c0, c1), 0.f);
    }
    *(f32x4*)(op + half * 8) = a;
    *(f32x4*)(op + half * 8 + 4) = b;
  }
}

// ---------- vectorized qstage: BN+ReLU+quantize yh -> LDS i8 tile ----------
template <int CI>
static __device__ __forceinline__ void qstage4(
    const u16* __restrict__ yhin, const float2* cfl, char* atile,
    int n, int h0, int tid) {
  for (int task = tid; task < (CI / 4) * 24; task += 256) {
    int co4 = task / 24, rem = task - co4 * 24;
    int rr = rem >> 2, w8 = rem & 3;
    int irow = h0 - 1 + rr;
    if (irow < 0 || irow > 31) continue;
    const u16* src = yhin + (size_t)(co4 * 4) * PTOT + (n << 10) + (irow << 5) + w8 * 8;
    u16x8 v0 = *(const u16x8*)(src);
    u16x8 v1 = *(const u16x8*)(src + PTOT);
    u16x8 v2 = *(const u16x8*)(src + 2 * (size_t)PTOT);
    u16x8 v3 = *(const u16x8*)(src + 3 * (size_t)PTOT);
    float2 c0 = cfl[co4 * 4], c1 = cfl[co4 * 4 + 1];
    float2 c2 = cfl[co4 * 4 + 2], c3 = cfl[co4 * 4 + 3];
    u32* dst = (u32*)&atile[(rr * 34 + 1 + w8 * 8) * CI + co4 * 4];
#pragma unroll
    for (int w = 0; w < 8; ++w) {
      u32 q0 = (u32)min((int)rintf(fmaxf(fmaf(bf2f(v0[w]), c0.x, c0.y), 0.f) * 128.f), 127);
      u32 q1 = (u32)min((int)rintf(fmaxf(fmaf(bf2f(v1[w]), c1.x, c1.y), 0.f) * 128.f), 127);
      u32 q2 = (u32)min((int)rintf(fmaxf(fmaf(bf2f(v2[w]), c2.x, c2.y), 0.f) * 128.f), 127);
      u32 q3 = (u32)min((int)rintf(fmaxf(fmaf(bf2f(v3[w]), c3.x, c3.y), 0.f) * 128.f), 127);
      dst[w * (CI / 4)] = q0 | (q1 << 8) | (q2 << 16) | (q3 << 24);
    }
  }
}

// ---------- shared conv epilogue (runtime nfw guard) ----------
template <int NFW, int MF>
static __device__ __forceinline__ void conv_epilogue(
    i32x4 (&acc)[MF][NFW], int nfw, int lane, int wave, int mbase,
    u16* __restrict__ yh, double* __restrict__ stb, int ststride) {
  float yv[MF][NFW][4];
#pragma unroll
  for (int mf = 0; mf < MF; ++mf)
#pragma unroll
    for (int nf = 0; nf < NFW; ++nf)
      if (nf < nfw) {
        int col = nf * 16 + (lane & 15);
        int pix = mbase + mf * 16 + ((lane >> 4) << 2);
        u16x4 o;
#pragma unroll
        for (int r = 0; r < 4; ++r) {
          float v = (float)acc[mf][nf][r] * 6.103515625e-05f;  // 2^-14 (exact)
          yv[mf][nf][r] = v;
          o[r] = bf_rne(v);
        }
        *(u16x4*)&yh[(size_t)col * PTOT + pix] = o;
      }

  float s1[NFW], s2[NFW];
#pragma unroll
  for (int nf = 0; nf < NFW; ++nf) { s1[nf] = 0.f; s2[nf] = 0.f; }
#pragma unroll
  for (int mf = 0; mf < MF; ++mf)
#pragma unroll
    for (int nf = 0; nf < NFW; ++nf)
      if (nf < nfw)
#pragma unroll
        for (int r = 0; r < 4; ++r) {
          float v = yv[mf][nf][r];
          s1[nf] += v;
          s2[nf] += v * v;
        }
#pragma unroll
  for (int m = 16; m <= 32; m <<= 1)
#pragma unroll
    for (int nf = 0; nf < NFW; ++nf) {
      s1[nf] += __shfl_xor(s1[nf], m);
      s2[nf] += __shfl_xor(s2[nf], m);
    }
  __shared__ float red[4][NFW][16][2];
  if (lane < 16)
#pragma unroll
    for (int nf = 0; nf < NFW; ++nf) {
      red[wave][nf][lane][0] = s1[nf];
      red[wave][nf][lane][1] = s2[nf];
    }
  __syncthreads();
  const int t = threadIdx.x;
  if (t < 16 * nfw) {
    int nf = t >> 4, l = t & 15;
    float a = red[0][nf][l][0] + red[1][nf][l][0] + red[2][nf][l][0] + red[3][nf][l][0];
    float b = red[0][nf][l][1] + red[1][nf][l][1] + red[2][nf][l][1] + red[3][nf][l][1];
    int rep = blockIdx.x & (NREP - 1);
    atomicAdd(&stb[rep * ststride + 2 * t], (double)a);
    atomicAdd(&stb[rep * ststride + 2 * t + 1], (double)b);
  }
}

// ---------- merged 1x1 convs {b1,b2a,b3a} + fused pool+b4 (blockIdx.y=3) ----------
__global__ __launch_bounds__(256, 4) void cstat1x1_kernel(
    const char* __restrict__ xq, const char* __restrict__ bpk,
    double* __restrict__ st, u16* __restrict__ yh) {
  constexpr int NFW = 6;
  constexpr int MF = 2;
  __shared__ __align__(16) char smem[30720];

  const int b = blockIdx.y;  // uniform
  const int nfw = (b == 0) ? 4 : (b == 1) ? 6 : (b == 2) ? 1 : 2;
  const int bpo = (b == 0) ? 0 : (b == 1) ? 12288 : (b == 2) ? 153600 : 175104;
  const int sto = (b == 0) ? 0 : (b == 1) ? 256 * NREP
                           : (b == 2) ? 3 * 256 * NREP : 6 * 256 * NREP;
  const int yho = (b == 0) ? 0 : (b == 1) ? 64 : (b == 2) ? 160 : 176;
  const char* bp = bpk + bpo;
  double* stb = st + sto;
  u16* yhb = yh + (size_t)yho * PTOT;

  const int tid = threadIdx.x;
  char* btile = smem;
  char* pooled = smem + 6144;
  const int bsz = nfw * 3 * 1024;
  for (int s = tid * 16; s < bsz; s += 4096)
    *(uint4*)&btile[s] = *(const uint4*)(bp + s);

  const int p0 = blockIdx.x * 128;
  if (b == 3) {  // build pooled tile (identical clamped 3x3 max over xq)
    const int n = p0 >> 10, h0 = (p0 & 1023) >> 5;
    for (int task = tid; task < 128 * 12; task += 256) {
      int px = task / 12, c16 = task - px * 12;
      int h = h0 + (px >> 5), w = px & 31;
      int m[16];
#pragma unroll
      for (int j = 0; j < 16; ++j) m[j] = -127;
      for (int dh = -1; dh <= 1; ++dh) {
        int hh = h + dh; if (hh < 0 || hh > 31) continue;
        for (int dw = -1; dw <= 1; ++dw) {
          int ww = w + dw; if (ww < 0 || ww > 31) continue;
          uint4 v = *(const uint4*)&xq[((size_t)((n << 10) + (hh << 5) + ww)) * 192 +
                                       c16 * 16];
          const char* bb = reinterpret_cast<const char*>(&v);
#pragma unroll
          for (int t = 0; t < 16; ++t) {
            int bv = (int)bb[t];
            m[t] = bv > m[t] ? bv : m[t];
          }
        }
      }
      uint4 o;
      char* ob = reinterpret_cast<char*>(&o);
#pragma unroll
      for (int t = 0; t < 16; ++t) ob[t] = (char)m[t];
      *(uint4*)&pooled[px * 192 + c16 * 16] = o;
    }
  }
  __syncthreads();

  const int lane = tid & 63;
  const int wave = tid >> 6;
  const int mbase = p0 + wave * 32;

  uint aoff[MF];
#pragma unroll
  for (int mf = 0; mf < MF; ++mf) {
    int px = (b == 3) ? (wave * 32 + mf * 16 + (lane & 15))
                      : (mbase + mf * 16 + (lane & 15));
    aoff[mf] = (uint)px * 192u;
  }
  const uint klane = (uint)(lane >> 4) * 16u;
  const uint blane = (uint)lane * 16u;

  i32x4 acc[MF][NFW];
#pragma unroll
  for (int i = 0; i < MF; ++i)
#pragma unroll
    for (int j = 0; j < NFW; ++j) acc[i][j] = {0, 0, 0, 0};

#pragma unroll
  for (int c = 0; c < 3; ++c) {
    i32x4 af[MF];
#pragma unroll
    for (int mf = 0; mf < MF; ++mf)
      af[mf] = (b == 3) ? *(const i32x4*)&pooled[aoff[mf] + (uint)c * 64u + klane]
                        : *(const i32x4*)(xq + (aoff[mf] + (uint)c * 64u + klane));
    i32x4 bfr[NFW];
#pragma unroll
    for (int nf = 0; nf < NFW; ++nf)
      if (nf < nfw)
        bfr[nf] = *(const i32x4*)&btile[(uint)((c * nfw + nf) * 1024) + blane];
#pragma unroll
    for (int mf = 0; mf < MF; ++mf)
#pragma unroll
      for (int nf = 0; nf < NFW; ++nf)
        if (nf < nfw)
          acc[mf][nf] = __builtin_amdgcn_mfma_i32_16x16x64_i8(af[mf], bfr[nf],
                                                              acc[mf][nf], 0, 0, 0);
  }

  conv_epilogue<NFW, MF>(acc, nfw, lane, wave, mbase, yhb, stb, 256);
}

// ---------- merged b2b + b3b + bnout(b1,b4) (blockIdx.y in 0..4) ----------
struct M2Args {
  const u16* yhin0; const double* stp0; const float* g0; const float* be0;
  const char* bp0; double* stb0; u16* yho0;   // b2b
  const u16* yhin1; const double* stp1; const float* g1; const float* be1;
  const char* bp1; double* stb1; u16* yho1;   // b3b
  const u16* yh; const double* st; float* out;
  const float* gb1; const float* beb1; const float* gb4; const float* beb4;
};

__global__ __launch_bounds__(256, 4) void cstat9m_kernel(M2Args A) {
  __shared__ __align__(16) char atile[6 * 34 * 96 + 64];  // b2b size; b3b uses prefix
  __shared__ __align__(16) char btile[6144];               // b3b only
  __shared__ float2 cfl[96];

  const int tid = threadIdx.x;
  const int y = blockIdx.y;

  if (y >= 2) {
    // ---- streaming: bnout for b1 (y=2: co 0-31, y=3: co 32-63) and b4 (y=4) ----
    int lco = ((y == 3) ? 32 : 0) + (blockIdx.x >> 5);
    int chunk = blockIdx.x & 31;
    if (y == 4)
      bnout_one(A.yh + (size_t)176 * PTOT, A.st + 6 * 256 * NREP, A.gb4, A.beb4,
                A.out, 224, lco, chunk, tid);
    else
      bnout_one(A.yh, A.st, A.gb1, A.beb1, A.out, 0, lco, chunk, tid);
    return;
  }

  if (y == 0) {
    // ===== b2b: qstage(b2a) -> 3x3 96->128; wave = 128 px x 32 co (MF=8,NFW=2).
    // Per chunk: 2 B-loads (2 KB) per 16 MFMA -> 128 B/MFMA (4x less L2 demand).
    constexpr int CI = 96;
    constexpr int CPR = 5;
    constexpr int NCH = 15;
    constexpr int MF = 8;
    constexpr int NFW = 2;
    constexpr int TILE = 6 * 34 * CI;

    if (tid < CI) {
      double s1d = 0., s2d = 0.;
#pragma unroll
      for (int r = 0; r < NREP; ++r) {
        s1d += A.stp0[r * 256 + 2 * tid];
        s2d += A.stp0[r * 256 + 2 * tid + 1];
      }
      double m = s1d * (1.0 / PTOT);
      double v = s2d * (1.0 / PTOT) - m * m;
      double inv = 1.0 / sqrt(v + 1e-5);
      double c0 = (double)A.g0[tid] * inv;
      cfl[tid] = make_float2((float)c0, (float)((double)A.be0[tid] - m * c0));
    }
    {
      uint4 z = {0, 0, 0, 0};
      for (int s = tid * 16; s < TILE + 64; s += 4096) *(uint4*)&atile[s] = z;
    }
    __syncthreads();

    const int p0 = blockIdx.x * 128;
    const int n = p0 >> 10, h0 = (p0 & 1023) >> 5;
    qstage4<CI>(A.yhin0, cfl, atile, n, h0, tid);
    __syncthreads();

    const int lane = tid & 63;
    const int cg = tid >> 6;  // wave = channel group (0..3)

    uint albase[MF];
#pragma unroll
    for (int mf = 0; mf < MF; ++mf) {
      int lp = mf * 16 + (lane & 15);  // local pixel in [0,128)
      albase[mf] = (uint)((((lp >> 5) + 1) * 34 + 1 + (lp & 31)) * CI);
    }
    const uint klane = (uint)(lane >> 4) * 16u;
    const uint blane = (uint)lane * 16u;

    i32x4 acc[MF][NFW];
#pragma unroll
    for (int i = 0; i < MF; ++i)
#pragma unroll
      for (int j = 0; j < NFW; ++j) acc[i][j] = {0, 0, 0, 0};

#pragma unroll 3
    for (int c = 0; c < NCH; ++c) {
      int rr = c / CPR, o = (c - rr * CPR) * 64;
      uint koff = (uint)((rr - 1) * 34 * CI + o - CI);
      i32x4 bfr[NFW];
#pragma unroll
      for (int nf = 0; nf < NFW; ++nf)
        bfr[nf] = *(const i32x4*)(A.bp0 +
                                  ((uint)((c * 8 + cg * 2 + nf) * 1024) + blane));
#pragma unroll
      for (int mf = 0; mf < MF; ++mf) {
        i32x4 af = *(const i32x4*)&atile[albase[mf] + koff + klane];
#pragma unroll
        for (int nf = 0; nf < NFW; ++nf)
          acc[mf][nf] = __builtin_amdgcn_mfma_i32_16x16x64_i8(af, bfr[nf],
                                                              acc[mf][nf], 0, 0, 0);
      }
    }

    // ---- epilogue: wave owns channels cg*32..cg*32+31 over ALL 128 px ----
    float s1[NFW], s2[NFW];
#pragma unroll
    for (int nf = 0; nf < NFW; ++nf) { s1[nf] = 0.f; s2[nf] = 0.f; }
#pragma unroll
    for (int mf = 0; mf < MF; ++mf)
#pragma unroll
      for (int nf = 0; nf < NFW; ++nf) {
        int col = cg * 32 + nf * 16 + (lane & 15);
        int pix = p0 + mf * 16 + ((lane >> 4) << 2);
        u16x4 o;
#pragma unroll
        for (int r = 0; r < 4; ++r) {
          float v = (float)acc[mf][nf][r] * 6.103515625e-05f;
          s1[nf] += v;
          s2[nf] += v * v;
          o[r] = bf_rne(v);
        }
        *(u16x4*)&A.yho0[(size_t)col * PTOT + pix] = o;
      }
#pragma unroll
    for (int m = 16; m <= 32; m <<= 1)
#pragma unroll
      for (int nf = 0; nf < NFW; ++nf) {
        s1[nf] += __shfl_xor(s1[nf], m);
        s2[nf] += __shfl_xor(s2[nf], m);
      }
    if (lane < 16) {
      int rep = blockIdx.x & (NREP - 1);
#pragma unroll
      for (int nf = 0; nf < NFW; ++nf) {
        int ch = cg * 32 + nf * 16 + lane;
        atomicAdd(&A.stb0[rep * 256 + 2 * ch], (double)s1[nf]);
        atomicAdd(&A.stb0[rep * 256 + 2 * ch + 1], (double)s2[nf]);
      }
    }
  } else {
    // ===== b3b: qstage(b3a) -> 3x3 16->32, B in LDS =====
    constexpr int CI = 16;
    constexpr int NCH = 3;
    constexpr int MF = 2;
    constexpr int NFW = 2;
    constexpr int TILE = 6 * 34 * CI;

    if (tid < CI) {
      double s1d = 0., s2d = 0.;
#pragma unroll
      for (int r = 0; r < NREP; ++r) {
        s1d += A.stp1[r * 256 + 2 * tid];
        s2d += A.stp1[r * 256 + 2 * tid + 1];
      }
      double m = s1d * (1.0 / PTOT);
      double v = s2d * (1.0 / PTOT) - m * m;
      double inv = 1.0 / sqrt(v + 1e-5);
      double c0 = (double)A.g1[tid] * inv;
      cfl[tid] = make_float2((float)c0, (float)((double)A.be1[tid] - m * c0));
    }
    for (int s = tid * 16; s < 6144; s += 4096)
      *(uint4*)&btile[s] = *(const uint4*)(A.bp1 + s);
    {
      uint4 z = {0, 0, 0, 0};
      for (int s = tid * 16; s < TILE + 64; s += 4096) *(uint4*)&atile[s] = z;
    }
    __syncthreads();

    const int p0 = blockIdx.x * 128;
    const int n = p0 >> 10, h0 = (p0 & 1023) >> 5;
    qstage4<CI>(A.yhin1, cfl, atile, n, h0, tid);
    __syncthreads();

    const int lane = tid & 63;
    const int wave = tid >> 6;
    const int mbase = blockIdx.x * 128 + wave * 32;

    uint albase[MF];
#pragma unroll
    for (int mf = 0; mf < MF; ++mf) {
      int lp = wave * 32 + mf * 16 + (lane & 15);
      albase[mf] = (uint)((((lp >> 5) + 1) * 34 + 1 + (lp & 31)) * CI);
    }
    const uint klane = (uint)(lane >> 4) * 16u;
    const uint blane = (uint)lane * 16u;

    i32x4 acc[MF][NFW];
#pragma unroll
    for (int i = 0; i < MF; ++i)
#pragma unroll
      for (int j = 0; j < NFW; ++j) acc[i][j] = {0, 0, 0, 0};

#pragma unroll
    for (int c = 0; c < NCH; ++c) {
      uint koff = (uint)((c - 1) * 34 * CI - CI);
      i32x4 af[MF];
#pragma unroll
      for (int mf = 0; mf < MF; ++mf)
        af[mf] = *(const i32x4*)&atile[albase[mf] + koff + klane];
      i32x4 bfr[NFW];
#pragma unroll
      for (int nf = 0; nf < NFW; ++nf)
        bfr[nf] = *(const i32x4*)&btile[(uint)((c * 2 + nf) * 1024) + blane];
#pragma unroll
      for (int mf = 0; mf < MF; ++mf)
#pragma unroll
        for (int nf = 0; nf < NFW; ++nf)
          acc[mf][nf] = __builtin_amdgcn_mfma_i32_16x16x64_i8(af[mf], bfr[nf],
                                                              acc[mf][nf], 0, 0, 0);
    }

    conv_epilogue<NFW, MF>(acc, NFW, lane, wave, mbase, A.yho1, A.stb1, 256);
  }
}

// ---------- b3c conv + bnout(b2b) co-dispatch (blockIdx.y in 0..4) ----------
struct M3Args {
  const u16* yhin; const double* stp; const float* gp; const float* bep;
  const char* bp; double* stb; u16* yho;       // b3c conv
  const u16* yh2b; const double* st2b; const float* g2b; const float* be2b;
  float* out;                                   // bnout b2b
};

__global__ __launch_bounds__(256, 4) void cstat9c_kernel(M3Args A) {
  constexpr int CI = 32;
  constexpr int CPR = 2;
  constexpr int NCH = 6;
  constexpr int NFW = 2;
  constexpr int MF = 2;
  constexpr int TILE = 6 * 34 * CI;

  __shared__ __align__(16) char atile[TILE + 64];
  __shared__ __align__(16) char btile[12288];
  __shared__ float2 cfl[CI];

  const int tid = threadIdx.x;
  const int y = blockIdx.y;

  if (y >= 1) {
    // ---- streaming: bnout for b2b channels 64..191 (4 slices of 32) ----
    int lco = (y - 1) * 32 + (blockIdx.x >> 5);
    int chunk = blockIdx.x & 31;
    bnout_one(A.yh2b, A.st2b, A.g2b, A.be2b, A.out, 64, lco, chunk, tid);
    return;
  }

  if (tid < CI) {
    double s1d = 0., s2d = 0.;
#pragma unroll
    for (int r = 0; r < NREP; ++r) {
      s1d += A.stp[r * 256 + 2 * tid];
      s2d += A.stp[r * 256 + 2 * tid + 1];
    }
    double m = s1d * (1.0 / PTOT);
    double v = s2d * (1.0 / PTOT) - m * m;
    double inv = 1.0 / sqrt(v + 1e-5);
    double c0 = (double)A.gp[tid] * inv;
    cfl[tid] = make_float2((float)c0, (float)((double)A.bep[tid] - m * c0));
  }
  for (int s = tid * 16; s < 12288; s += 4096)
    *(uint4*)&btile[s] = *(const uint4*)(A.bp + s);
  {
    uint4 z = {0, 0, 0, 0};
    for (int s = tid * 16; s < TILE + 64; s += 4096) *(uint4*)&atile[s] = z;
  }
  __syncthreads();

  const int p0 = blockIdx.x * 128;
  const int n = p0 >> 10, h0 = (p0 & 1023) >> 5;
  qstage4<CI>(A.yhin, cfl, atile, n, h0, tid);
  __syncthreads();

  const int lane = tid & 63;
  const int wave = tid >> 6;
  const int mbase = blockIdx.x * 128 + wave * 32;

  uint albase[MF];
#pragma unroll
  for (int mf = 0; mf < MF; ++mf) {
    int lp = wave * 32 + mf * 16 + (lane & 15);
    albase[mf] = (uint)((((lp >> 5) + 1) * 34 + 1 + (lp & 31)) * CI);
  }
  const uint klane = (uint)(lane >> 4) * 16u;
  const uint blane = (uint)lane * 16u;

  i32x4 acc[MF][NFW];
#pragma unroll
  for (int i = 0; i < MF; ++i)
#pragma unroll
    for (int j = 0; j < NFW; ++j) acc[i][j] = {0, 0, 0, 0};

#pragma unroll 2
  for (int c = 0; c < NCH; ++c) {
    int rr = c / CPR, o = (c - rr * CPR) * 64;
    uint koff = (uint)((rr - 1) * 34 * CI + o - CI);
    i32x4 af[MF];
#pragma unroll
    for (int mf = 0; mf < MF; ++mf)
      af[mf] = *(const i32x4*)&atile[albase[mf] + koff + klane];
    i32x4 bfr[NFW];
#pragma unroll
    for (int nf = 0; nf < NFW; ++nf)
      bfr[nf] = *(const i32x4*)&btile[(uint)((c * 2 + nf) * 1024) + blane];
#pragma unroll
    for (int mf = 0; mf < MF; ++mf)
#pragma unroll
      for (int nf = 0; nf < NFW; ++nf)
        acc[mf][nf] = __builtin_amdgcn_mfma_i32_16x16x64_i8(af[mf], bfr[nf],
                                                            acc[mf][nf], 0, 0, 0);
  }

  conv_epilogue<NFW, MF>(acc, NFW, lane, wave, mbase, A.yho, A.stb, 256);
}

// ---------- final: bnout for b3c channels only ----------
__global__ __launch_bounds__(256) void bnout_fin_kernel(
    const u16* __restrict__ yh, const double* __restrict__ st,
    const float* __restrict__ g, const float* __restrict__ be,
    float* __restrict__ out) {
  bnout_one(yh, st, g, be, out, 192, blockIdx.y, blockIdx.x, threadIdx.x);
}

extern "C" void kernel_launch(void* const* d_in, const int* in_sizes, int n_in,
                              void* d_out, int out_size, void* d_ws, size_t ws_size,
                              hipStream_t stream) {
  const float* x = (const float*)d_in[0];
  float* out = (float*)d_out;
  char* ws = (char*)d_ws;

  // ---- workspace layout (total 155,599,872 B) ----
  if (ws_size < 155599872ull) return;
  char* xq  = ws;                            // [PTOT][192] i8        = 25,165,824 B
  u16* yh   = (u16*)(ws + 50331648ull);      // [400][PTOT] bf16     = 104,857,600 B
  // yh slices (channel offsets): b1 0, b2a 64, b3a 160, b4 176, b2b 208,
  //                              b3b 336, b3c 368
  char* bpk = ws + 155189248ull;             // packed i8 weights        181,248 B
  double* st = (double*)(ws + 155370496ull); // 7 x NREP x 256 doubles   229,376 B

  hipMemsetAsync(st, 0, 7 * NREP * 256 * 8, stream);

  WPtrs wp;
  const int widx[7] = {1, 5, 9, 13, 17, 21, 25};
  for (int i = 0; i < 7; ++i) wp.p[i] = (const float*)d_in[widx[i]];
  wpack_kernel<<<708, 256, 0, stream>>>(wp, bpk);

  quantx_kernel<<<dim3(16, 3, 128), 256, 0, stream>>>(x, xq);

  double* stB[7];
  for (int b = 0; b < 7; ++b) stB[b] = st + (size_t)b * NREP * 256;

  // ---- merged 1x1 convs b1/b2a/b3a + fused pool+b4 ----
  cstat1x1_kernel<<<dim3(1024, 4), 256, 0, stream>>>(xq, bpk, st, yh);

  // ---- b2b + b3b convs, co-dispatched with bnout(b1) and bnout(b4) ----
  M2Args A;
  A.yhin0 = yh + (size_t)64 * PTOT;  A.stp0 = stB[1];
  A.g0 = (const float*)d_in[7];      A.be0 = (const float*)d_in[8];
  A.bp0 = bpk + 30720;               A.stb0 = stB[2];
  A.yho0 = yh + (size_t)208 * PTOT;
  A.yhin1 = yh + (size_t)160 * PTOT; A.stp1 = stB[3];
  A.g1 = (const float*)d_in[15];     A.be1 = (const float*)d_in[16];
  A.bp1 = bpk + 156672;              A.stb1 = stB[4];
  A.yho1 = yh + (size_t)336 * PTOT;
  A.yh = yh; A.st = st; A.out = out;
  A.gb1 = (const float*)d_in[3];     A.beb1 = (const float*)d_in[4];
  A.gb4 = (const float*)d_in[27];    A.beb4 = (const float*)d_in[28];
  cstat9m_kernel<<<dim3(1024, 5), 256, 0, stream>>>(A);

  // ---- b3c conv, co-dispatched with bnout(b2b 128 ch) ----
  M3Args C;
  C.yhin = yh + (size_t)336 * PTOT;  C.stp = stB[4];
  C.gp = (const float*)d_in[19];     C.bep = (const float*)d_in[20];
  C.bp = bpk + 162816;               C.stb = stB[5];
  C.yho = yh + (size_t)368 * PTOT;
  C.yh2b = yh + (size_t)208 * PTOT;  C.st2b = stB[2];
  C.g2b = (const float*)d_in[11];    C.be2b = (const float*)d_in[12];
  C.out = out;
  cstat9c_kernel<<<dim3(1024, 5), 256, 0, stream>>>(C);

  // ---- final: bnout for b3c's 32 channels ----
  bnout_fin_kernel<<<dim3(32, 32), 256, 0, stream>>>(
      yh + (size_t)368 * PTOT, stB[5], (const float*)d_in[23],
      (const float*)d_in[24], out);
}